// Round 1
// baseline (1587.899 us; speedup 1.0000x reference)
//
#include <hip/hip_runtime.h>
#include <math.h>

namespace {

constexpr int Bb   = 128;
constexpr int Ss   = 196;
constexpr int DIN  = 512;
constexpr int Hh   = 8;
constexpr int DKc  = 32;
constexpr int DVc  = 128;
constexpr int QKVD = 1536;   // H*(2*DK+DV)
constexpr int PIN  = 1024;   // H*DV
constexpr int Mrows = Bb * Ss; // 25088
constexpr float EPSc   = 1e-3f;
constexpr float SCALEc = 0.17677669529663687f; // 32^-0.5

// ---------------- GEMM + fused BatchNorm epilogue ----------------
// C[m][n] = (sum_k A[m][k]*W[k][n] + bias[n] - mean[n]) * gamma[n]*rsqrt(var[n]+eps) + beta[n]
template<int N, int K>
__global__ __launch_bounds__(256)
void gemm_bn(const float* __restrict__ A, const float* __restrict__ W,
             const float* __restrict__ bias, const float* __restrict__ gamma,
             const float* __restrict__ beta, const float* __restrict__ mean,
             const float* __restrict__ var, float* __restrict__ C)
{
    constexpr int BM = 128, BN = 128, BK = 16;
    __shared__ float As[BK][BM];   // [k][m] so compute reads are broadcast/2-way
    __shared__ float Bs[BK][BN];
    const int t  = threadIdx.x;
    const int tm = t >> 4;         // 0..15  (within wave: 4 distinct -> A broadcast)
    const int tn = t & 15;         // 0..15  (B reads 16 addrs x b128 = 2-way, free)
    constexpr int ntiles = N / BN;
    const int m0 = (int)(blockIdx.x / ntiles) * BM;
    const int n0 = (int)(blockIdx.x % ntiles) * BN;

    float acc[8][8];
#pragma unroll
    for (int i = 0; i < 8; ++i)
#pragma unroll
        for (int j = 0; j < 8; ++j) acc[i][j] = 0.f;

    for (int k0 = 0; k0 < K; k0 += BK) {
        // stage A tile 128x16 (float4 along K, transposed scatter into As)
#pragma unroll
        for (int i = 0; i < 2; ++i) {
            int fid = t + 256 * i;
            int am  = fid >> 2;
            int ak  = (fid & 3) * 4;
            float4 v = *(const float4*)(A + (size_t)(m0 + am) * K + k0 + ak);
            As[ak + 0][am] = v.x;
            As[ak + 1][am] = v.y;
            As[ak + 2][am] = v.z;
            As[ak + 3][am] = v.w;
        }
        // stage B tile 16x128 (float4 along N, direct)
#pragma unroll
        for (int i = 0; i < 2; ++i) {
            int fid = t + 256 * i;
            int bk  = fid >> 5;
            int bn  = (fid & 31) * 4;
            *(float4*)(&Bs[bk][bn]) = *(const float4*)(W + (size_t)(k0 + bk) * N + n0 + bn);
        }
        __syncthreads();
#pragma unroll
        for (int kk = 0; kk < BK; ++kk) {
            float4 a0 = *(const float4*)(&As[kk][tm * 8]);
            float4 a1 = *(const float4*)(&As[kk][tm * 8 + 4]);
            float4 b0 = *(const float4*)(&Bs[kk][tn * 8]);
            float4 b1 = *(const float4*)(&Bs[kk][tn * 8 + 4]);
            float av[8] = {a0.x, a0.y, a0.z, a0.w, a1.x, a1.y, a1.z, a1.w};
            float bv[8] = {b0.x, b0.y, b0.z, b0.w, b1.x, b1.y, b1.z, b1.w};
#pragma unroll
            for (int i = 0; i < 8; ++i)
#pragma unroll
                for (int j = 0; j < 8; ++j) acc[i][j] = fmaf(av[i], bv[j], acc[i][j]);
        }
        __syncthreads();
    }
    // fused BN epilogue
#pragma unroll
    for (int j = 0; j < 8; ++j) {
        int n = n0 + tn * 8 + j;
        float s  = gamma[n] * rsqrtf(var[n] + EPSc);
        float tv = fmaf(bias[n] - mean[n], s, beta[n]);
#pragma unroll
        for (int i = 0; i < 8; ++i) {
            int m = m0 + tm * 8 + i;
            C[(size_t)m * N + n] = fmaf(acc[i][j], s, tv);
        }
    }
}

// ---------------- fused attention + scrambled-transpose + hard_swish ----------------
// One block per (b, h, query-chunk of 28). 256 threads.
// LDS budget (<= 64KB): sc[28*196] + vbuf[28*128] + region(kT[32*196]+q[28*32] / avT[128*28])
__global__ __launch_bounds__(256)
void attn_kernel(const float* __restrict__ qkv, float* __restrict__ hidden)
{
    __shared__ float smem[16240];            // 64,960 B
    float* sc     = smem;                    // 28*196 = 5488
    float* vbuf   = smem + 5488;             // 28*128 = 3584
    float* region = smem + 9072;             // 7168 floats
    float* kT     = region;                  // [32][196]
    float* qlds   = region + 32 * 196;       // [28][32]
    float* avT    = region;                  // [128][28] (reuses kT/q after phase A)

    const int t     = threadIdx.x;
    const int bid   = blockIdx.x;
    const int chunk = bid % 7;
    const int bh    = bid / 7;
    const int b     = bh >> 3;
    const int h     = bh & 7;
    const int s0    = chunk * 28;
    const float* base = qkv + (size_t)b * Ss * QKVD + h * (2 * DKc + DVc);

    // ---- stage K transposed: kT[kk][j] = K[j][kk] ----
    for (int fid = t; fid < 196 * 8; fid += 256) {
        int row = fid >> 3, c4 = (fid & 7) * 4;
        float4 v = *(const float4*)(base + (size_t)row * QKVD + DKc + c4);
        kT[(c4 + 0) * 196 + row] = v.x;
        kT[(c4 + 1) * 196 + row] = v.y;
        kT[(c4 + 2) * 196 + row] = v.z;
        kT[(c4 + 3) * 196 + row] = v.w;
    }
    // ---- stage Q chunk: 28 x 32 ----
    for (int fid = t; fid < 28 * 8; fid += 256) {
        int row = fid >> 3, c4 = (fid & 7) * 4;
        *(float4*)(qlds + row * 32 + c4) =
            *(const float4*)(base + (size_t)(s0 + row) * QKVD + c4);
    }
    __syncthreads();

    // ---- phase A: scores[ss][j] = SCALE * q[ss] . k[j] ----
    if (t < 196) {
        for (int ss = 0; ss < 28; ++ss) {
            float a = 0.f;
#pragma unroll
            for (int k4 = 0; k4 < 8; ++k4) {
                float4 qv = *(const float4*)(qlds + ss * 32 + k4 * 4);
                a = fmaf(qv.x, kT[(k4 * 4 + 0) * 196 + t], a);
                a = fmaf(qv.y, kT[(k4 * 4 + 1) * 196 + t], a);
                a = fmaf(qv.z, kT[(k4 * 4 + 2) * 196 + t], a);
                a = fmaf(qv.w, kT[(k4 * 4 + 3) * 196 + t], a);
            }
            sc[ss * 196 + t] = a * SCALEc;
        }
    }
    __syncthreads();

    // ---- phase B: softmax along j for each of the 28 rows ----
    if (t < 28) {
        float m = -1e30f;
        for (int j = 0; j < 196; ++j) m = fmaxf(m, sc[t * 196 + j]);
        float sum = 0.f;
        for (int j = 0; j < 196; ++j) {
            float e = __expf(sc[t * 196 + j] - m);
            sc[t * 196 + j] = e;
            sum += e;
        }
        float inv = 1.f / sum;
        for (int j = 0; j < 196; ++j) sc[t * 196 + j] *= inv;
    }
    __syncthreads();

    // ---- phase C: AV. 8 query-groups of 32 lanes; each lane does 4 d's (b128 reads) ----
    const int qg = t >> 5;          // 0..7
    const int dp = (t & 31) * 4;    // d base 0..124
    float acc[4][4];
#pragma unroll
    for (int p = 0; p < 4; ++p)
#pragma unroll
        for (int e = 0; e < 4; ++e) acc[p][e] = 0.f;

    for (int vs = 0; vs < 7; ++vs) {
        // stage 28 V rows [vs*28, vs*28+28)
        for (int fid = t; fid < 28 * 32; fid += 256) {
            int row = fid >> 5, c4 = (fid & 31) * 4;
            *(float4*)(vbuf + row * 128 + c4) =
                *(const float4*)(base + (size_t)(vs * 28 + row) * QKVD + 2 * DKc + c4);
        }
        __syncthreads();
#pragma unroll
        for (int p = 0; p < 4; ++p) {
            int ss = p * 8 + qg;
            if (ss < 28) {
                for (int jj = 0; jj < 28; ++jj) {
                    float pw = sc[ss * 196 + vs * 28 + jj];   // broadcast per 32-lane group
                    float4 v = *(const float4*)(vbuf + jj * 128 + dp);
                    acc[p][0] = fmaf(pw, v.x, acc[p][0]);
                    acc[p][1] = fmaf(pw, v.y, acc[p][1]);
                    acc[p][2] = fmaf(pw, v.z, acc[p][2]);
                    acc[p][3] = fmaf(pw, v.w, acc[p][3]);
                }
            }
        }
        __syncthreads();
    }

    // ---- stash av transposed: avT[d][ss] (kT/q region is dead now) ----
#pragma unroll
    for (int p = 0; p < 4; ++p) {
        int ss = p * 8 + qg;
        if (ss < 28) {
#pragma unroll
            for (int e = 0; e < 4; ++e) avT[(dp + e) * 28 + ss] = acc[p][e];
        }
    }
    __syncthreads();

    // ---- phase D: hard_swish + scrambled store: hidden flat f = h*25088 + d*196 + s ----
    float* hb = hidden + (size_t)b * (Ss * PIN) + (size_t)h * (DVc * Ss);
    for (int idx = t; idx < 128 * 28; idx += 256) {
        int d  = idx / 28;
        int ss = idx % 28;
        float x = avT[idx];                        // avT flat layout is d*28+ss
        float hs = x * fminf(fmaxf(x + 3.f, 0.f), 6.f) * (1.f / 6.f);
        hb[d * Ss + s0 + ss] = hs;                 // runs of 28 consecutive floats
    }
}

} // namespace

extern "C" void kernel_launch(void* const* d_in, const int* in_sizes, int n_in,
                              void* d_out, int out_size, void* d_ws, size_t ws_size,
                              hipStream_t stream)
{
    const float* x    = (const float*)d_in[0];
    const float* Wqkv = (const float*)d_in[1];
    const float* bqkv = (const float*)d_in[2];
    const float* g1   = (const float*)d_in[3];
    const float* be1  = (const float*)d_in[4];
    const float* mu1  = (const float*)d_in[5];
    const float* va1  = (const float*)d_in[6];
    const float* Wp   = (const float*)d_in[7];
    const float* bp   = (const float*)d_in[8];
    const float* g2   = (const float*)d_in[9];
    const float* be2  = (const float*)d_in[10];
    const float* mu2  = (const float*)d_in[11];
    const float* va2  = (const float*)d_in[12];

    float* qkv    = (float*)d_ws;                      // 25088*1536 floats
    float* hidden = qkv + (size_t)Mrows * QKVD;        // 25088*1024 floats
    float* out    = (float*)d_out;

    // GEMM1 + BN: x[25088,512] @ Wqkv[512,1536] -> qkv
    gemm_bn<QKVD, DIN><<<dim3(196 * (QKVD / 128)), dim3(256), 0, stream>>>(
        x, Wqkv, bqkv, g1, be1, mu1, va1, qkv);

    // fused attention (+ transpose scramble + hard_swish) -> hidden[25088,1024]
    attn_kernel<<<dim3(Bb * Hh * 7), dim3(256), 0, stream>>>(qkv, hidden);

    // GEMM2 + BN: hidden[25088,1024] @ Wp[1024,512] -> out
    gemm_bn<DIN, PIN><<<dim3(196 * (DIN / 128)), dim3(256), 0, stream>>>(
        hidden, Wp, bp, g2, be2, mu2, va2, out);
}

// Round 2
// 879.487 us; speedup vs baseline: 1.8055x; 1.8055x over previous
//
#include <hip/hip_runtime.h>
#include <math.h>

namespace {

constexpr int Bb   = 128;
constexpr int Ss   = 196;
constexpr int DIN  = 512;
constexpr int Hh   = 8;
constexpr int DKc  = 32;
constexpr int DVc  = 128;
constexpr int QKVD = 1536;   // H*(2*DK+DV)
constexpr int PIN  = 1024;   // H*DV
constexpr int Mrows = Bb * Ss; // 25088
constexpr float EPSc   = 1e-3f;
constexpr float SCALEc = 0.17677669529663687f; // 32^-0.5

typedef __bf16 bf16x8 __attribute__((ext_vector_type(8)));
typedef __bf16 bf16x4 __attribute__((ext_vector_type(4)));
typedef float  f32x4  __attribute__((ext_vector_type(4)));

// ---- async global->LDS, 16B per lane; lds base must be wave-uniform ----
__device__ __forceinline__ void gl_lds16(const void* g, void* l) {
    __builtin_amdgcn_global_load_lds(
        (const __attribute__((address_space(1))) void*)g,
        (__attribute__((address_space(3))) void*)l, 16, 0, 0);
}

// ---------------- fp32 -> bf16 elementwise convert (x) ----------------
__global__ __launch_bounds__(256)
void cvt_f32_bf16(const float* __restrict__ in, __bf16* __restrict__ out, int n4)
{
    int i = blockIdx.x * 256 + threadIdx.x;
    if (i < n4) {
        float4 v = ((const float4*)in)[i];
        bf16x4 o = { (__bf16)v.x, (__bf16)v.y, (__bf16)v.z, (__bf16)v.w };
        ((bf16x4*)out)[i] = o;
    }
}

// ---------------- W[K][N] fp32 -> WT[N][K] bf16 ----------------
__global__ __launch_bounds__(256)
void transpose_cvt(const float* __restrict__ W, __bf16* __restrict__ WT, int K, int N)
{
    __shared__ float tile[32][33];
    const int n0 = blockIdx.x * 32, k0 = blockIdx.y * 32;
    const int tx = threadIdx.x & 31, ty = threadIdx.x >> 5;   // ty 0..7
#pragma unroll
    for (int i = ty; i < 32; i += 8)
        tile[i][tx] = W[(size_t)(k0 + i) * N + n0 + tx];
    __syncthreads();
#pragma unroll
    for (int i = ty; i < 32; i += 8)
        WT[(size_t)(n0 + i) * K + k0 + tx] = (__bf16)tile[tx][i];
}

// ---------------- bf16 MFMA GEMM + fused BatchNorm epilogue ----------------
// C[m][n] = (sum_k A[m][k]*B[k][n] + bias[n] - mean[n])*gamma[n]*rsqrt(var[n]+eps) + beta[n]
// A: bf16 [M][K] row-major.  BT: bf16 [N][K] row-major (pre-transposed B).
// Block: 256 thr = 4 waves, tile 128x128, BK=32. Wave w -> 64x64 (4x4 MFMA tiles).
template<int N, int K>
__global__ __launch_bounds__(256)
void gemm_bn_mfma(const __bf16* __restrict__ A, const __bf16* __restrict__ BT,
                  const float* __restrict__ bias, const float* __restrict__ gamma,
                  const float* __restrict__ beta, const float* __restrict__ mean,
                  const float* __restrict__ var, float* __restrict__ C)
{
    constexpr int BM = 128, BN = 128, BK = 32;
    __shared__ __bf16 As[BM * BK];   // [128][32] row-major, 8 KB
    __shared__ __bf16 Bs[BN * BK];   // [128][32] row-major, 8 KB

    const int t    = threadIdx.x;
    const int wave = t >> 6;
    const int lane = t & 63;
    const int lr   = lane & 15;      // row-in-16-tile (A) / col n (B,C)
    const int q    = lane >> 4;      // quad

    constexpr int ntiles = N / BN;
    const int m0 = (int)(blockIdx.x / ntiles) * BM;
    const int n0 = (int)(blockIdx.x % ntiles) * BN;
    const int wm = (wave & 1) * 64;
    const int wn = (wave >> 1) * 64;

    // staging: thread t loads 16B: row = t>>2 (+64 for chunk1), kchunk = t&3
    const __bf16* aG0 = A  + (size_t)(m0 + (t >> 2)) * K + (t & 3) * 8;
    const __bf16* aG1 = aG0 + (size_t)64 * K;
    const __bf16* bG0 = BT + (size_t)(n0 + (t >> 2)) * K + (t & 3) * 8;
    const __bf16* bG1 = bG0 + (size_t)64 * K;
    char* lA = (char*)As + wave * 1024;   // + chunk*4096
    char* lB = (char*)Bs + wave * 1024;

    f32x4 acc[4][4] = {};

    for (int k0 = 0; k0 < K; k0 += BK) {
        gl_lds16(aG0 + k0, lA);
        gl_lds16(aG1 + k0, lA + 4096);
        gl_lds16(bG0 + k0, lB);
        gl_lds16(bG1 + k0, lB + 4096);
        __syncthreads();   // drains vmcnt (global_load_lds) + orders LDS

        bf16x8 aF[4], bF[4];
#pragma unroll
        for (int i = 0; i < 4; ++i)
            aF[i] = *(const bf16x8*)(As + (wm + i * 16 + lr) * 32 + q * 8);
#pragma unroll
        for (int j = 0; j < 4; ++j)
            bF[j] = *(const bf16x8*)(Bs + (wn + j * 16 + lr) * 32 + q * 8);
#pragma unroll
        for (int i = 0; i < 4; ++i)
#pragma unroll
            for (int j = 0; j < 4; ++j)
                acc[i][j] = __builtin_amdgcn_mfma_f32_16x16x32_bf16(
                    aF[i], bF[j], acc[i][j], 0, 0, 0);
        __syncthreads();   // protect LDS before next stage overwrites
    }

    // fused BN epilogue. This thread's cols: n0+wn+j*16+lr; rows: m0+wm+i*16+q*4+r
#pragma unroll
    for (int j = 0; j < 4; ++j) {
        const int n = n0 + wn + j * 16 + lr;
        const float s  = gamma[n] * rsqrtf(var[n] + EPSc);
        const float tv = fmaf(bias[n] - mean[n], s, beta[n]);
#pragma unroll
        for (int i = 0; i < 4; ++i) {
            const int mrow = m0 + wm + i * 16 + q * 4;
#pragma unroll
            for (int r = 0; r < 4; ++r)
                C[(size_t)(mrow + r) * N + n] = fmaf(acc[i][j][r], s, tv);
        }
    }
}

// ---------------- fused attention + scrambled-transpose + hard_swish ----------------
// One block per (b, h, query-chunk of 28). 256 threads. hidden written as bf16.
__global__ __launch_bounds__(256)
void attn_kernel(const float* __restrict__ qkv, __bf16* __restrict__ hidden)
{
    __shared__ float smem[16240];            // 64,960 B
    float* sc     = smem;                    // 28*196 = 5488
    float* vbuf   = smem + 5488;             // 28*128 = 3584
    float* region = smem + 9072;             // 7168 floats
    float* kT     = region;                  // [32][196]
    float* qlds   = region + 32 * 196;       // [28][32]
    float* avT    = region;                  // [128][28] (reuses kT/q after phase A)

    const int t     = threadIdx.x;
    const int bid   = blockIdx.x;
    const int chunk = bid % 7;
    const int bh    = bid / 7;
    const int b     = bh >> 3;
    const int h     = bh & 7;
    const int s0    = chunk * 28;
    const float* base = qkv + (size_t)b * Ss * QKVD + h * (2 * DKc + DVc);

    // ---- stage K transposed: kT[kk][j] = K[j][kk] ----
    for (int fid = t; fid < 196 * 8; fid += 256) {
        int row = fid >> 3, c4 = (fid & 7) * 4;
        float4 v = *(const float4*)(base + (size_t)row * QKVD + DKc + c4);
        kT[(c4 + 0) * 196 + row] = v.x;
        kT[(c4 + 1) * 196 + row] = v.y;
        kT[(c4 + 2) * 196 + row] = v.z;
        kT[(c4 + 3) * 196 + row] = v.w;
    }
    // ---- stage Q chunk: 28 x 32 ----
    for (int fid = t; fid < 28 * 8; fid += 256) {
        int row = fid >> 3, c4 = (fid & 7) * 4;
        *(float4*)(qlds + row * 32 + c4) =
            *(const float4*)(base + (size_t)(s0 + row) * QKVD + c4);
    }
    __syncthreads();

    // ---- phase A: scores[ss][j] = SCALE * q[ss] . k[j] ----
    if (t < 196) {
        for (int ss = 0; ss < 28; ++ss) {
            float a = 0.f;
#pragma unroll
            for (int k4 = 0; k4 < 8; ++k4) {
                float4 qv = *(const float4*)(qlds + ss * 32 + k4 * 4);
                a = fmaf(qv.x, kT[(k4 * 4 + 0) * 196 + t], a);
                a = fmaf(qv.y, kT[(k4 * 4 + 1) * 196 + t], a);
                a = fmaf(qv.z, kT[(k4 * 4 + 2) * 196 + t], a);
                a = fmaf(qv.w, kT[(k4 * 4 + 3) * 196 + t], a);
            }
            sc[ss * 196 + t] = a * SCALEc;
        }
    }
    __syncthreads();

    // ---- phase B: softmax along j for each of the 28 rows ----
    if (t < 28) {
        float m = -1e30f;
        for (int j = 0; j < 196; ++j) m = fmaxf(m, sc[t * 196 + j]);
        float sum = 0.f;
        for (int j = 0; j < 196; ++j) {
            float e = __expf(sc[t * 196 + j] - m);
            sc[t * 196 + j] = e;
            sum += e;
        }
        float inv = 1.f / sum;
        for (int j = 0; j < 196; ++j) sc[t * 196 + j] *= inv;
    }
    __syncthreads();

    // ---- phase C: AV ----
    const int qg = t >> 5;          // 0..7
    const int dp = (t & 31) * 4;    // d base 0..124
    float acc[4][4];
#pragma unroll
    for (int p = 0; p < 4; ++p)
#pragma unroll
        for (int e = 0; e < 4; ++e) acc[p][e] = 0.f;

    for (int vs = 0; vs < 7; ++vs) {
        for (int fid = t; fid < 28 * 32; fid += 256) {
            int row = fid >> 5, c4 = (fid & 31) * 4;
            *(float4*)(vbuf + row * 128 + c4) =
                *(const float4*)(base + (size_t)(vs * 28 + row) * QKVD + 2 * DKc + c4);
        }
        __syncthreads();
#pragma unroll
        for (int p = 0; p < 4; ++p) {
            int ss = p * 8 + qg;
            if (ss < 28) {
                for (int jj = 0; jj < 28; ++jj) {
                    float pw = sc[ss * 196 + vs * 28 + jj];
                    float4 v = *(const float4*)(vbuf + jj * 128 + dp);
                    acc[p][0] = fmaf(pw, v.x, acc[p][0]);
                    acc[p][1] = fmaf(pw, v.y, acc[p][1]);
                    acc[p][2] = fmaf(pw, v.z, acc[p][2]);
                    acc[p][3] = fmaf(pw, v.w, acc[p][3]);
                }
            }
        }
        __syncthreads();
    }

    // ---- stash av transposed: avT[d][ss] ----
#pragma unroll
    for (int p = 0; p < 4; ++p) {
        int ss = p * 8 + qg;
        if (ss < 28) {
#pragma unroll
            for (int e = 0; e < 4; ++e) avT[(dp + e) * 28 + ss] = acc[p][e];
        }
    }
    __syncthreads();

    // ---- phase D: hard_swish + scrambled store (bf16) ----
    __bf16* hb = hidden + (size_t)b * (Ss * PIN) + (size_t)h * (DVc * Ss);
    for (int idx = t; idx < 128 * 28; idx += 256) {
        int d  = idx / 28;
        int ss = idx % 28;
        float x = avT[idx];
        float hs = x * fminf(fmaxf(x + 3.f, 0.f), 6.f) * (1.f / 6.f);
        hb[d * Ss + s0 + ss] = (__bf16)hs;
    }
}

} // namespace

extern "C" void kernel_launch(void* const* d_in, const int* in_sizes, int n_in,
                              void* d_out, int out_size, void* d_ws, size_t ws_size,
                              hipStream_t stream)
{
    const float* x    = (const float*)d_in[0];
    const float* Wqkv = (const float*)d_in[1];
    const float* bqkv = (const float*)d_in[2];
    const float* g1   = (const float*)d_in[3];
    const float* be1  = (const float*)d_in[4];
    const float* mu1  = (const float*)d_in[5];
    const float* va1  = (const float*)d_in[6];
    const float* Wp   = (const float*)d_in[7];
    const float* bp   = (const float*)d_in[8];
    const float* g2   = (const float*)d_in[9];
    const float* be2  = (const float*)d_in[10];
    const float* mu2  = (const float*)d_in[11];
    const float* va2  = (const float*)d_in[12];

    // workspace layout (bytes):
    char* ws = (char*)d_ws;
    float*  qkv    = (float*)ws;                            // 25088*1536*4 = 154,140,672
    __bf16* hidden = (__bf16*)(ws + 154140672);             // 25088*1024*2 =  51,380,224
    __bf16* xb     = (__bf16*)(ws + 154140672 + 51380224);  // 25088*512*2  =  25,690,112
    __bf16* WT1    = (__bf16*)(ws + 231211008);             // 1536*512*2   =   1,572,864
    __bf16* WT2    = (__bf16*)(ws + 232783872);             // 512*1024*2   =   1,048,576
    float*  out    = (float*)d_out;

    // prepasses: x -> bf16 ; W -> bf16 transposed
    cvt_f32_bf16<<<dim3((Mrows * DIN / 4 + 255) / 256), dim3(256), 0, stream>>>(
        x, xb, Mrows * DIN / 4);
    transpose_cvt<<<dim3(QKVD / 32, DIN / 32), dim3(256), 0, stream>>>(Wqkv, WT1, DIN, QKVD);
    transpose_cvt<<<dim3(DIN / 32, PIN / 32), dim3(256), 0, stream>>>(Wp, WT2, PIN, DIN);

    // GEMM1 + BN: xb[25088,512] @ Wqkv -> qkv (fp32)
    gemm_bn_mfma<QKVD, DIN><<<dim3(196 * (QKVD / 128)), dim3(256), 0, stream>>>(
        xb, WT1, bqkv, g1, be1, mu1, va1, qkv);

    // fused attention -> hidden (bf16, scrambled layout == linear reshape)
    attn_kernel<<<dim3(Bb * Hh * 7), dim3(256), 0, stream>>>(qkv, hidden);

    // GEMM2 + BN: hidden[25088,1024] @ Wp -> out (fp32)
    gemm_bn_mfma<DIN, PIN><<<dim3(196 * (DIN / 128)), dim3(256), 0, stream>>>(
        hidden, WT2, bp, g2, be2, mu2, va2, out);
}

// Round 3
// 337.888 us; speedup vs baseline: 4.6995x; 2.6029x over previous
//
#include <hip/hip_runtime.h>
#include <math.h>

namespace {

constexpr int Bb   = 128;
constexpr int Ss   = 196;
constexpr int DIN  = 512;
constexpr int Hh   = 8;
constexpr int DKc  = 32;
constexpr int DVc  = 128;
constexpr int QKVD = 1536;   // H*(2*DK+DV)
constexpr int PIN  = 1024;   // H*DV
constexpr int Mrows = Bb * Ss; // 25088
constexpr float EPSc   = 1e-3f;
constexpr float SCALEc = 0.17677669529663687f; // 32^-0.5

typedef __bf16 bf16x8 __attribute__((ext_vector_type(8)));
typedef __bf16 bf16x4 __attribute__((ext_vector_type(4)));
typedef float  f32x4  __attribute__((ext_vector_type(4)));

// VT layout: [bh][quarter(4)][ 8192 elems ], quarter row stride 232 elems.
constexpr int VT_STRIDE = 232;                 // elems; 464 B = 16B-aligned, 2-way banks
constexpr size_t VT_QELEMS = 8192;             // padded quarter (32 rows x 232 = 7424 used)
constexpr size_t VT_BH = 4 * VT_QELEMS;        // 32768 elems per (b,h)

__device__ __forceinline__ void gl_lds16(const void* g, void* l) {
    __builtin_amdgcn_global_load_lds(
        (const __attribute__((address_space(1))) void*)g,
        (__attribute__((address_space(3))) void*)l, 16, 0, 0);
}

// ---------------- fp32 -> bf16 elementwise convert (x) ----------------
__global__ __launch_bounds__(256)
void cvt_f32_bf16(const float* __restrict__ in, __bf16* __restrict__ out, int n4)
{
    int i = blockIdx.x * 256 + threadIdx.x;
    if (i < n4) {
        float4 v = ((const float4*)in)[i];
        bf16x4 o = { (__bf16)v.x, (__bf16)v.y, (__bf16)v.z, (__bf16)v.w };
        ((bf16x4*)out)[i] = o;
    }
}

// ---------------- W[K][N] fp32 -> WT[N][K] bf16 ----------------
__global__ __launch_bounds__(256)
void transpose_cvt(const float* __restrict__ W, __bf16* __restrict__ WT, int K, int N)
{
    __shared__ float tile[32][33];
    const int n0 = blockIdx.x * 32, k0 = blockIdx.y * 32;
    const int tx = threadIdx.x & 31, ty = threadIdx.x >> 5;
#pragma unroll
    for (int i = ty; i < 32; i += 8)
        tile[i][tx] = W[(size_t)(k0 + i) * N + n0 + tx];
    __syncthreads();
#pragma unroll
    for (int i = ty; i < 32; i += 8)
        WT[(size_t)(n0 + i) * K + k0 + tx] = (__bf16)tile[tx][i];
}

// ---------------- GEMM1: x@Wqkv + BN, scatter epilogue ----------------
// Q/K channels (ch<64 within each head's 192) -> qkvO bf16 [25088][1536] (V cols untouched)
// V channels -> VTp[bh][d>>5][ (d&31)*232 + s ] bf16 (pre-transposed, packed 4-s stores)
__global__ __launch_bounds__(256)
void gemm1_bn_scatter(const __bf16* __restrict__ A, const __bf16* __restrict__ BT,
                      const float* __restrict__ bias, const float* __restrict__ gamma,
                      const float* __restrict__ beta, const float* __restrict__ mean,
                      const float* __restrict__ var,
                      __bf16* __restrict__ qkvO, __bf16* __restrict__ VTp)
{
    constexpr int N = QKVD, K = DIN;
    constexpr int BM = 128, BN = 128, BK = 32;
    __shared__ __bf16 As[BM * BK];
    __shared__ __bf16 Bs[BN * BK];

    const int t    = threadIdx.x;
    const int wave = t >> 6;
    const int lane = t & 63;
    const int lr   = lane & 15;
    const int q    = lane >> 4;

    constexpr int ntiles = N / BN;
    const int m0 = (int)(blockIdx.x / ntiles) * BM;
    const int n0 = (int)(blockIdx.x % ntiles) * BN;
    const int wm = (wave & 1) * 64;
    const int wn = (wave >> 1) * 64;

    const __bf16* aG0 = A  + (size_t)(m0 + (t >> 2)) * K + (t & 3) * 8;
    const __bf16* aG1 = aG0 + (size_t)64 * K;
    const __bf16* bG0 = BT + (size_t)(n0 + (t >> 2)) * K + (t & 3) * 8;
    const __bf16* bG1 = bG0 + (size_t)64 * K;
    char* lA = (char*)As + wave * 1024;
    char* lB = (char*)Bs + wave * 1024;

    f32x4 acc[4][4] = {};

    for (int k0 = 0; k0 < K; k0 += BK) {
        gl_lds16(aG0 + k0, lA);
        gl_lds16(aG1 + k0, lA + 4096);
        gl_lds16(bG0 + k0, lB);
        gl_lds16(bG1 + k0, lB + 4096);
        __syncthreads();
        bf16x8 aF[4], bF[4];
#pragma unroll
        for (int i = 0; i < 4; ++i)
            aF[i] = *(const bf16x8*)(As + (wm + i * 16 + lr) * 32 + q * 8);
#pragma unroll
        for (int j = 0; j < 4; ++j)
            bF[j] = *(const bf16x8*)(Bs + (wn + j * 16 + lr) * 32 + q * 8);
#pragma unroll
        for (int i = 0; i < 4; ++i)
#pragma unroll
            for (int j = 0; j < 4; ++j)
                acc[i][j] = __builtin_amdgcn_mfma_f32_16x16x32_bf16(
                    aF[i], bF[j], acc[i][j], 0, 0, 0);
        __syncthreads();
    }

    // rows of this thread: mrow(i) = m0+wm+i*16+q*4 (+r). 4-aligned, 196|4 => never crosses b.
    int bidx[4], sidx[4];
#pragma unroll
    for (int i = 0; i < 4; ++i) {
        int mrow = m0 + wm + i * 16 + q * 4;
        bidx[i] = mrow / 196;
        sidx[i] = mrow - bidx[i] * 196;
    }
#pragma unroll
    for (int j = 0; j < 4; ++j) {
        const int n  = n0 + wn + j * 16 + lr;
        const int h  = n / 192;
        const int ch = n - h * 192;
        const float s  = gamma[n] * rsqrtf(var[n] + EPSc);
        const float tv = fmaf(bias[n] - mean[n], s, beta[n]);
        if (ch < 64) {
            // Q/K -> qkv bf16 (scattered b16 stores)
#pragma unroll
            for (int i = 0; i < 4; ++i) {
                const int mrow = m0 + wm + i * 16 + q * 4;
#pragma unroll
                for (int r = 0; r < 4; ++r)
                    qkvO[(size_t)(mrow + r) * N + n] = (__bf16)fmaf(acc[i][j][r], s, tv);
            }
        } else {
            // V -> VTp (packed 4-s bf16 stores)
            const int d = ch - 64;
            const size_t vb = (size_t)(bidx[0] * 0) /*dummy*/;
            (void)vb;
#pragma unroll
            for (int i = 0; i < 4; ++i) {
                const size_t base = (size_t)(bidx[i] * 8 + h) * VT_BH
                                  + (size_t)(d >> 5) * VT_QELEMS
                                  + (size_t)(d & 31) * VT_STRIDE + sidx[i];
                bf16x4 pk = { (__bf16)fmaf(acc[i][j][0], s, tv),
                              (__bf16)fmaf(acc[i][j][1], s, tv),
                              (__bf16)fmaf(acc[i][j][2], s, tv),
                              (__bf16)fmaf(acc[i][j][3], s, tv) };
                *(bf16x4*)(VTp + base) = pk;
            }
        }
    }
}

// ---------------- generic bf16 MFMA GEMM + BN (fp32 out) — GEMM2 ----------------
template<int N, int K>
__global__ __launch_bounds__(256)
void gemm_bn_mfma(const __bf16* __restrict__ A, const __bf16* __restrict__ BT,
                  const float* __restrict__ bias, const float* __restrict__ gamma,
                  const float* __restrict__ beta, const float* __restrict__ mean,
                  const float* __restrict__ var, float* __restrict__ C)
{
    constexpr int BM = 128, BN = 128, BK = 32;
    __shared__ __bf16 As[BM * BK];
    __shared__ __bf16 Bs[BN * BK];
    const int t    = threadIdx.x;
    const int wave = t >> 6;
    const int lane = t & 63;
    const int lr   = lane & 15;
    const int q    = lane >> 4;
    constexpr int ntiles = N / BN;
    const int m0 = (int)(blockIdx.x / ntiles) * BM;
    const int n0 = (int)(blockIdx.x % ntiles) * BN;
    const int wm = (wave & 1) * 64;
    const int wn = (wave >> 1) * 64;
    const __bf16* aG0 = A  + (size_t)(m0 + (t >> 2)) * K + (t & 3) * 8;
    const __bf16* aG1 = aG0 + (size_t)64 * K;
    const __bf16* bG0 = BT + (size_t)(n0 + (t >> 2)) * K + (t & 3) * 8;
    const __bf16* bG1 = bG0 + (size_t)64 * K;
    char* lA = (char*)As + wave * 1024;
    char* lB = (char*)Bs + wave * 1024;
    f32x4 acc[4][4] = {};
    for (int k0 = 0; k0 < K; k0 += BK) {
        gl_lds16(aG0 + k0, lA);
        gl_lds16(aG1 + k0, lA + 4096);
        gl_lds16(bG0 + k0, lB);
        gl_lds16(bG1 + k0, lB + 4096);
        __syncthreads();
        bf16x8 aF[4], bF[4];
#pragma unroll
        for (int i = 0; i < 4; ++i)
            aF[i] = *(const bf16x8*)(As + (wm + i * 16 + lr) * 32 + q * 8);
#pragma unroll
        for (int j = 0; j < 4; ++j)
            bF[j] = *(const bf16x8*)(Bs + (wn + j * 16 + lr) * 32 + q * 8);
#pragma unroll
        for (int i = 0; i < 4; ++i)
#pragma unroll
            for (int j = 0; j < 4; ++j)
                acc[i][j] = __builtin_amdgcn_mfma_f32_16x16x32_bf16(
                    aF[i], bF[j], acc[i][j], 0, 0, 0);
        __syncthreads();
    }
#pragma unroll
    for (int j = 0; j < 4; ++j) {
        const int n = n0 + wn + j * 16 + lr;
        const float s  = gamma[n] * rsqrtf(var[n] + EPSc);
        const float tv = fmaf(bias[n] - mean[n], s, beta[n]);
#pragma unroll
        for (int i = 0; i < 4; ++i) {
            const int mrow = m0 + wm + i * 16 + q * 4;
#pragma unroll
            for (int r = 0; r < 4; ++r)
                C[(size_t)(mrow + r) * N + n] = fmaf(acc[i][j][r], s, tv);
        }
    }
}

// ---------------- MFMA attention: QK^T -> reg softmax -> PV -> hard_swish ----------------
// block = (b, h, qc); wave w owns q-tile qt = qc*4+w (16 q-rows). S padded to 224.
// LDS: Kb[208][40] (16640 B) | P: 4 x [16][232] (29696 B) | Vt quarter (16384 B) = 62720 B
__global__ __launch_bounds__(256)
void attn_mfma(const __bf16* __restrict__ qkv, const __bf16* __restrict__ VTp,
               __bf16* __restrict__ hidden)
{
    __shared__ __align__(16) char smem[62720];
    __bf16* Kb = (__bf16*)smem;

    const int t = threadIdx.x;
    const int wave = t >> 6, lane = t & 63;
    const int lr = lane & 15, q = lane >> 4;
    const int bid = blockIdx.x;
    const int qc = bid & 3;
    const int bh = bid >> 2;
    const int b = bh >> 3, h = bh & 7;
    const __bf16* qkvb = qkv + (size_t)b * 196 * QKVD + h * 192;

    // ---- stage K: rows s=0..195, ch 32..63 -> Kb[s][40] ----
    for (int fid = t; fid < 196 * 4; fid += 256) {
        int s = fid >> 2, c = fid & 3;
        bf16x8 v = *(const bf16x8*)(qkvb + (size_t)s * QKVD + 32 + c * 8);
        *(bf16x8*)(Kb + s * 40 + c * 8) = v;
    }
    __syncthreads();

    const int qt = qc * 4 + wave;              // q-tile; valid rows only for qt<=12
    const bool wactive = (qt <= 12);
    __bf16* Pw = (__bf16*)(smem + 16640 + wave * 7424);   // [16][232]

    if (wactive) {
        // Q fragment straight from global
        int sQ = qt * 16 + lr; if (sQ > 195) sQ = 195;
        bf16x8 aQ = *(const bf16x8*)(qkv + ((size_t)b * 196 + sQ) * QKVD + h * 192 + q * 8);

        f32x4 sc[13];
#pragma unroll
        for (int nt = 0; nt < 13; ++nt) {
            bf16x8 bK = *(const bf16x8*)(Kb + (nt * 16 + lr) * 40 + q * 8);
            f32x4 z = {0.f, 0.f, 0.f, 0.f};
            sc[nt] = __builtin_amdgcn_mfma_f32_16x16x32_bf16(aQ, bK, z, 0, 0, 0);
        }
        // ---- register softmax over the 208 cols (cols>=196 masked) ----
        float mrow[4] = {-1e30f, -1e30f, -1e30f, -1e30f};
#pragma unroll
        for (int nt = 0; nt < 13; ++nt) {
            const bool valid = (nt < 12) | (lr < 4);
#pragma unroll
            for (int r = 0; r < 4; ++r) {
                float x = sc[nt][r] * SCALEc;
                sc[nt][r] = x;
                if (valid) mrow[r] = fmaxf(mrow[r], x);
            }
        }
#pragma unroll
        for (int d = 1; d < 16; d <<= 1)
#pragma unroll
            for (int r = 0; r < 4; ++r)
                mrow[r] = fmaxf(mrow[r], __shfl_xor(mrow[r], d, 64));
        float l[4] = {0.f, 0.f, 0.f, 0.f};
#pragma unroll
        for (int nt = 0; nt < 13; ++nt) {
            const bool valid = (nt < 12) | (lr < 4);
#pragma unroll
            for (int r = 0; r < 4; ++r) {
                float e = valid ? __expf(sc[nt][r] - mrow[r]) : 0.f;
                sc[nt][r] = e;
                l[r] += e;
            }
        }
#pragma unroll
        for (int d = 1; d < 16; d <<= 1)
#pragma unroll
            for (int r = 0; r < 4; ++r)
                l[r] += __shfl_xor(l[r], d, 64);
        float inv[4];
#pragma unroll
        for (int r = 0; r < 4; ++r) inv[r] = 1.f / l[r];

        // ---- P to LDS in A-operand layout: P[m=quad*4+r][col] ----
#pragma unroll
        for (int nt = 0; nt < 13; ++nt)
#pragma unroll
            for (int r = 0; r < 4; ++r)
                Pw[(q * 4 + r) * 232 + nt * 16 + lr] = (__bf16)(sc[nt][r] * inv[r]);
        // zero cols 208..231
        for (int idx = lane; idx < 16 * 24; idx += 64) {
            int row = idx & 15, cz = 208 + (idx >> 4);
            Pw[row * 232 + cz] = (__bf16)0.f;
        }
    }

    // ---- PV over 4 dv-quarters, VT staged via global_load_lds (16 KB linear) ----
    const char* gV = (const char*)(VTp + (size_t)bh * VT_BH);
    char* ldsV = smem + 46336;
    const int sbase = qt * 16 + q * 4;
    const bool sval = wactive && (sbase + 3 < 196);
    __bf16* hb = hidden + (size_t)b * 200704 + (size_t)h * 25088;

    for (int q4 = 0; q4 < 4; ++q4) {
        const char* gq = gV + (size_t)q4 * 16384;
#pragma unroll
        for (int i = 0; i < 4; ++i)
            gl_lds16(gq + i * 4096 + wave * 1024 + lane * 16,
                     ldsV + i * 4096 + wave * 1024);
        __syncthreads();
        if (wactive) {
            f32x4 o0 = {0.f, 0.f, 0.f, 0.f}, o1 = {0.f, 0.f, 0.f, 0.f};
            const __bf16* Vl = (const __bf16*)ldsV;
#pragma unroll
            for (int kk = 0; kk < 7; ++kk) {
                bf16x8 aP = *(const bf16x8*)(Pw + lr * 232 + kk * 32 + q * 8);
                bf16x8 b0 = *(const bf16x8*)(Vl + lr * 232 + kk * 32 + q * 8);
                bf16x8 b1 = *(const bf16x8*)(Vl + (16 + lr) * 232 + kk * 32 + q * 8);
                o0 = __builtin_amdgcn_mfma_f32_16x16x32_bf16(aP, b0, o0, 0, 0, 0);
                o1 = __builtin_amdgcn_mfma_f32_16x16x32_bf16(aP, b1, o1, 0, 0, 0);
            }
            if (sval) {
#pragma unroll
                for (int nt2 = 0; nt2 < 2; ++nt2) {
                    f32x4 o = nt2 ? o1 : o0;
                    const int d = q4 * 32 + nt2 * 16 + lr;
                    bf16x4 pk;
#pragma unroll
                    for (int r = 0; r < 4; ++r) {
                        float x = o[r];
                        pk[r] = (__bf16)(x * fminf(fmaxf(x + 3.f, 0.f), 6.f) * (1.f / 6.f));
                    }
                    *(bf16x4*)(hb + (size_t)d * 196 + sbase) = pk;
                }
            }
        }
        if (q4 < 3) __syncthreads();
    }
}

} // namespace

extern "C" void kernel_launch(void* const* d_in, const int* in_sizes, int n_in,
                              void* d_out, int out_size, void* d_ws, size_t ws_size,
                              hipStream_t stream)
{
    const float* x    = (const float*)d_in[0];
    const float* Wqkv = (const float*)d_in[1];
    const float* bqkv = (const float*)d_in[2];
    const float* g1   = (const float*)d_in[3];
    const float* be1  = (const float*)d_in[4];
    const float* mu1  = (const float*)d_in[5];
    const float* va1  = (const float*)d_in[6];
    const float* Wp   = (const float*)d_in[7];
    const float* bp   = (const float*)d_in[8];
    const float* g2   = (const float*)d_in[9];
    const float* be2  = (const float*)d_in[10];
    const float* mu2  = (const float*)d_in[11];
    const float* va2  = (const float*)d_in[12];

    // workspace layout (bytes)
    char* ws = (char*)d_ws;
    __bf16* qkv    = (__bf16*)ws;                    // 25088*1536*2 = 77,070,336
    __bf16* VTp    = (__bf16*)(ws + 77070336);       // 1024*32768*2 = 67,108,864
    __bf16* hidden = (__bf16*)(ws + 144179200);      // 25088*1024*2 = 51,380,224
    __bf16* xb     = (__bf16*)(ws + 195559424);      // 25088*512*2  = 25,690,112
    __bf16* WT1    = (__bf16*)(ws + 221249536);      // 1536*512*2
    __bf16* WT2    = (__bf16*)(ws + 222822400);      // 512*1024*2
    float*  out    = (float*)d_out;

    cvt_f32_bf16<<<dim3((Mrows * DIN / 4 + 255) / 256), dim3(256), 0, stream>>>(
        x, xb, Mrows * DIN / 4);
    transpose_cvt<<<dim3(QKVD / 32, DIN / 32), dim3(256), 0, stream>>>(Wqkv, WT1, DIN, QKVD);
    transpose_cvt<<<dim3(DIN / 32, PIN / 32), dim3(256), 0, stream>>>(Wp, WT2, PIN, DIN);

    // GEMM1 + BN -> qkv bf16 (Q,K) + VTp (V pre-transposed)
    gemm1_bn_scatter<<<dim3(196 * (QKVD / 128)), dim3(256), 0, stream>>>(
        xb, WT1, bqkv, g1, be1, mu1, va1, qkv, VTp);

    // MFMA attention -> hidden bf16 (scrambled layout)
    attn_mfma<<<dim3(Bb * Hh * 4), dim3(256), 0, stream>>>(qkv, VTp, hidden);

    // GEMM2 + BN -> out fp32
    gemm_bn_mfma<DIN, PIN><<<dim3(196 * (DIN / 128)), dim3(256), 0, stream>>>(
        hidden, WT2, bp, g2, be2, mu2, va2, out);
}